// Round 16
// baseline (146.627 us; speedup 1.0000x reference)
//
#include <hip/hip_runtime.h>
#include <hip/hip_bf16.h>

// SineLayer: y[b,o] = sum_{i,d} sin(w_d*x[b,i]+p_d) * (scale_d*c[o,i,d]) + offs[o]
// GEMM: M=32768, N=512, K=4096, bf16 MFMA 32x32x16 (2382 TF rate vs 2075).
// R16: R13 sandwich + 32x32x16 MFMA + stronger unit-swizzle h^=(r>>2)&7
// (32-lane bijective -> conflict-free fragment reads at 32-row fragments).
// Per kt: [B-issue+x-pref] MFMA(kk0,kk1) | sins+A-write | MFMA(kk2,kk3) | CBAR(1).

#define BATCH 32768
#define NIN   256
#define NOUT  512
#define DDIM  16
#define BM    128
#define BN    512
#define BK    64
#define NKT   ((NIN*DDIM)/BK)     // 64 K-steps
#define TILE_BYTES (BN*BK*2)      // 64 KB per kt pre-swizzled B tile
#define ABYTES (BM*BK*2)          // 16 KB per A buffer
#define BBYTES (BN*BK*2)          // 64 KB per B buffer
#define EPSV  1e-8f
#define INV2PI 0.15915494309189535f

typedef short  bf16x8  __attribute__((ext_vector_type(8)));
typedef float  f32x16  __attribute__((ext_vector_type(16)));

static __device__ __forceinline__ ushort f2bf(float f) {
  union { __hip_bfloat16 h; ushort u; } cv;
  cv.h = __float2bfloat16(f);
  return cv.u;
}

static __device__ __forceinline__ uint cvt_pk(float lo, float hi) {
  uint r;
  asm("v_cvt_pk_bf16_f32 %0, %1, %2" : "=v"(r) : "v"(lo), "v"(hi));
  return r;
}

static __device__ __forceinline__ float sgpr_f(float v) {
  return __builtin_bit_cast(float,
      __builtin_amdgcn_readfirstlane(__builtin_bit_cast(int, v)));
}

// ---------------------------------------------------------------------------
// Prep: cb[o,k] pre-swizzled 512x64 tiles; row o = 128 B (8 16B units);
// unit h stored at h ^ ((o>>2)&7). Linear gll copy yields the LDS image.
// offs[o] = bias[o] + sum mu_d*scale_d*c[o,i,d].
// ---------------------------------------------------------------------------
__global__ __launch_bounds__(256) void prep_kernel(
    const float* __restrict__ omega, const float* __restrict__ phase,
    const float* __restrict__ c_basis, const float* __restrict__ bias,
    ushort* __restrict__ cb, float* __restrict__ offs)
{
  __shared__ float s_scale[DDIM];
  __shared__ float s_musc[DDIM];
  __shared__ float s_red[4];

  const int o = blockIdx.x;
  const int t = threadIdx.x;

  if (t < DDIM) {
    float w = omega[t];
    float p = phase[t];
    float mu  = expf(-0.5f * w * w) * sinf(p);
    float var = 0.5f * (1.0f - expf(-2.0f * w * w) * cosf(2.0f * p)) - mu * mu;
    float sd  = sqrtf(fmaxf(var, 0.0f));
    float sc  = 1.0f / (sd + EPSV);
    s_scale[t] = sc;
    s_musc[t]  = mu * sc;
  }
  __syncthreads();

  const float* cp = c_basis + ((size_t)o * NIN + t) * DDIM;
  float cv[DDIM];
  {
    const float4* cp4 = (const float4*)cp;
    float4 a = cp4[0], b = cp4[1], c = cp4[2], d = cp4[3];
    cv[0]=a.x; cv[1]=a.y; cv[2]=a.z; cv[3]=a.w;
    cv[4]=b.x; cv[5]=b.y; cv[6]=b.z; cv[7]=b.w;
    cv[8]=c.x; cv[9]=c.y; cv[10]=c.z; cv[11]=c.w;
    cv[12]=d.x; cv[13]=d.y; cv[14]=d.z; cv[15]=d.w;
  }

  float partial = 0.0f;
  uint pk[8];
#pragma unroll
  for (int d = 0; d < DDIM; d += 2) {
    partial += cv[d] * s_musc[d] + cv[d+1] * s_musc[d+1];
    ushort u0 = f2bf(cv[d]   * s_scale[d]);
    ushort u1 = f2bf(cv[d+1] * s_scale[d+1]);
    pk[d >> 1] = (uint)u0 | ((uint)u1 << 16);
  }

  {
    const int r  = o;                 // 0..511
    const int kt = t >> 2;
    const int fo = (r >> 2) & 7;
    char* tile = (char*)cb + (size_t)kt * TILE_BYTES + r * 128;
    const int u0 = (2 * (t & 3))     ^ fo;
    const int u1 = (2 * (t & 3) + 1) ^ fo;
    *(uint4*)(tile + u0 * 16) = make_uint4(pk[0], pk[1], pk[2], pk[3]);
    *(uint4*)(tile + u1 * 16) = make_uint4(pk[4], pk[5], pk[6], pk[7]);
  }

#pragma unroll
  for (int off = 32; off > 0; off >>= 1) partial += __shfl_down(partial, off, 64);
  if ((t & 63) == 0) s_red[t >> 6] = partial;
  __syncthreads();
  if (t == 0) offs[o] = bias[o] + s_red[0] + s_red[1] + s_red[2] + s_red[3];
}

// ---------------------------------------------------------------------------
// GEMM: 128x512 tile, BK=64, 512 threads (8 waves: 2m x 4n, wave = 64x128).
// 32x32x16 fragments: wave tile = 2 m-frags x 4 n-frags, acc = f32x16[2][4].
// LDS: A0[16K] A1[16K] B0[64K] B1[64K] = 160 KB.
// ---------------------------------------------------------------------------
__global__ __launch_bounds__(512, 2) void gemm_kernel(
    const float* __restrict__ x, const float* __restrict__ omega,
    const float* __restrict__ phase, const ushort* __restrict__ cb,
    const float* __restrict__ offs, float* __restrict__ out)
{
  extern __shared__ char lds[];

  const int t    = threadIdx.x;
  const int lane = t & 63;
  const int wid  = t >> 6;
  const int wm   = wid >> 2;       // 0..1
  const int wn   = wid & 3;        // 0..3
  const int row0 = blockIdx.x * BM;

  // uniform omega/phase in SGPRs (readfirstlane) -> zero VGPR cost
  float wv[DDIM], pv[DDIM];
#pragma unroll
  for (int d = 0; d < DDIM; ++d) {
    wv[d] = sgpr_f(omega[d] * INV2PI);
    pv[d] = sgpr_f(phase[d] * INV2PI);
  }

  f32x16 acc[2][4];
#pragma unroll
  for (int m = 0; m < 2; ++m)
#pragma unroll
    for (int n = 0; n < 4; ++n)
#pragma unroll
      for (int j = 0; j < 16; ++j) acc[m][n][j] = 0.f;

  // A staging: thread t -> row t>>2 (0..127), i-slot t&3; 1 x -> 16 sins
  const int arow = t >> 2;
  const int acol = t & 3;
  const float* xbase = x + (size_t)(row0 + arow) * NIN + acol;
  const int afo  = (arow >> 2) & 7;
  const int aw0  = arow * 128 + ((2 * acol)     ^ afo) * 16;
  const int aw1  = arow * 128 + ((2 * acol + 1) ^ afo) * 16;

  const int l31 = lane & 31;
  const int hi2 = lane >> 5;       // 0..1
  const int fr  = l31 >> 2;        // 0..7 (swizzle key, per-thread const)

#define GLL(s_, d_) __builtin_amdgcn_global_load_lds(                          \
      (const __attribute__((address_space(1))) void*)(s_),                     \
      (__attribute__((address_space(3))) void*)(d_), 16, 0, 0)

  // 8 global_load_lds: 64 KB B-tile kt_ -> B buffer sb_ (compile-time sb_)
#define ISSUE_B(kt_, sb_)                                                      \
  {                                                                            \
    const char* src = (const char*)cb + (size_t)(kt_) * TILE_BYTES             \
                      + wid * 8192 + lane * 16;                                \
    char* dst = lds + 32768 + (sb_) * BBYTES + wid * 8192;                     \
    GLL(src, dst);                 GLL(src + 1024, dst + 1024);                \
    GLL(src + 2048, dst + 2048);   GLL(src + 3072, dst + 3072);                \
    GLL(src + 4096, dst + 4096);   GLL(src + 5120, dst + 5120);                \
    GLL(src + 6144, dst + 6144);   GLL(src + 7168, dst + 7168);                \
  }

  // 16 sins -> 8 packed bf16-pair words via v_cvt_pk_bf16_f32
#define SINS_ALL(xx_)                                                          \
    _Pragma("unroll")                                                          \
    for (int d = 0; d < DDIM; d += 2) {                                        \
      float s0 = __builtin_amdgcn_sinf(fmaf(wv[d],   (xx_), pv[d]));           \
      float s1 = __builtin_amdgcn_sinf(fmaf(wv[d+1], (xx_), pv[d+1]));         \
      pk[d >> 1] = cvt_pk(s0, s1);                                             \
    }

  // two swizzled ds_write_b128 of the packed sins into A buffer sb_
#define A_WRITE2(sb_)                                                          \
    *(uint4*)(lds + (sb_) * ABYTES + aw0) = make_uint4(pk[0], pk[1], pk[2], pk[3]); \
    *(uint4*)(lds + (sb_) * ABYTES + aw1) = make_uint4(pk[4], pk[5], pk[6], pk[7]);

  // fragment read offset for (rowbase multiple of 32, kk): swizzled unit
#define FRAG_OFF(rb_, kk_) (((rb_) + l31) * 128 + (((2 * (kk_) + hi2) ^ fr) * 16))

  // one kk-pair (half_=0 -> kk 0,1 ; half_=1 -> kk 2,3): 2x(af[2],bfr[4],8 MFMA)
#define MFMA_2K(mb_, half_)                                                    \
  {                                                                            \
    const char* AsB = lds + (mb_) * ABYTES;                                    \
    const char* BsB = lds + 32768 + (mb_) * BBYTES;                            \
    _Pragma("unroll")                                                          \
    for (int kq = 0; kq < 2; ++kq) {                                           \
      const int kk = (half_) * 2 + kq;                                         \
      bf16x8 af[2], bfr[4];                                                    \
      _Pragma("unroll")                                                        \
      for (int m = 0; m < 2; ++m)                                              \
        af[m] = *(const bf16x8*)(AsB + FRAG_OFF(wm * 64 + m * 32, kk));        \
      _Pragma("unroll")                                                        \
      for (int n = 0; n < 4; ++n)                                              \
        bfr[n] = *(const bf16x8*)(BsB + FRAG_OFF(wn * 128 + n * 32, kk));      \
      __builtin_amdgcn_s_setprio(1);                                           \
      _Pragma("unroll")                                                        \
      for (int m = 0; m < 2; ++m)                                              \
        _Pragma("unroll")                                                      \
        for (int n = 0; n < 4; ++n)                                            \
          acc[m][n] = __builtin_amdgcn_mfma_f32_32x32x16_bf16(                 \
              af[m], bfr[n], acc[m][n], 0, 0, 0);                              \
      __builtin_amdgcn_s_setprio(0);                                           \
    }                                                                          \
  }

#define SB __builtin_amdgcn_sched_barrier(0);

#define CBAR(vm_)                                                              \
  __builtin_amdgcn_sched_barrier(0);                                           \
  asm volatile("s_waitcnt vmcnt(" #vm_ ") lgkmcnt(0)" ::: "memory");           \
  __builtin_amdgcn_s_barrier();                                                \
  __builtin_amdgcn_sched_barrier(0);

  // R13 sandwich body with 32x32 fragments
#define BODY(kt_, mb_, sb_, XU_, XL_)                                          \
  {                                                                            \
    ISSUE_B(((kt_) + 1 < NKT ? (kt_) + 1 : NKT - 1), sb_);                     \
    XL_ = xbase[((kt_) + 2 < NKT ? (kt_) + 2 : NKT - 1) * 4];                  \
    SB                                                                         \
    MFMA_2K(mb_, 0)                                                            \
    SB                                                                         \
    uint pk[8];                                                                \
    SINS_ALL(XU_)                                                              \
    A_WRITE2(sb_)                                                              \
    SB                                                                         \
    MFMA_2K(mb_, 1)                                                            \
    CBAR(1)                                                                    \
  }

  // ---- prologue ----
  float xs0, xs1;
  {
    float xp = xbase[0];
    SB
    ISSUE_B(0, 0);
    SB
    xs1 = xbase[4];
    SB
    {
      uint pk[8];
      SINS_ALL(xp)
      A_WRITE2(0)
    }
    CBAR(1)                       // drains B(0)+x(0), keeps xs1 in flight
  }

  for (int kt = 0; kt < NKT; kt += 2) {
    BODY(kt,     0, 1, xs1, xs0)
    BODY(kt + 1, 1, 0, xs0, xs1)
  }

  // ---- epilogue: y = acc + offs[o] ; C/D map: col=l31, row=(reg&3)+8(reg>>2)+4*hi2
#pragma unroll
  for (int n = 0; n < 4; ++n) {
    int col = wn * 128 + n * 32 + l31;
    float off = offs[col];
#pragma unroll
    for (int m = 0; m < 2; ++m) {
      int rbase = row0 + wm * 64 + m * 32 + hi2 * 4;
#pragma unroll
      for (int reg = 0; reg < 16; ++reg) {
        int row = rbase + (reg & 3) + 8 * (reg >> 2);
        out[(size_t)row * NOUT + col] = acc[m][n][reg] + off;
      }
    }
  }
}

// ---------------------------------------------------------------------------
extern "C" void kernel_launch(void* const* d_in, const int* in_sizes, int n_in,
                              void* d_out, int out_size, void* d_ws, size_t ws_size,
                              hipStream_t stream) {
  const float* x       = (const float*)d_in[0];
  const float* omega   = (const float*)d_in[1];
  const float* phase   = (const float*)d_in[2];
  const float* c_basis = (const float*)d_in[3];
  const float* bias    = (const float*)d_in[4];
  float* out = (float*)d_out;

  float*  offs = (float*)d_ws;
  ushort* cb   = (ushort*)((char*)d_ws + 2048);

  hipFuncSetAttribute((const void*)gemm_kernel,
                      hipFuncAttributeMaxDynamicSharedMemorySize, 163840);

  prep_kernel<<<NOUT, 256, 0, stream>>>(omega, phase, c_basis, bias, cb, offs);
  gemm_kernel<<<BATCH / BM, 512, 163840, stream>>>(x, omega, phase, cb, offs, out);
}

// Round 17
// 145.186 us; speedup vs baseline: 1.0099x; 1.0099x over previous
//
#include <hip/hip_runtime.h>
#include <hip/hip_bf16.h>

// SineLayer: y[b,o] = sum_{i,d} sin(w_d*x[b,i]+p_d) * (scale_d*c[o,i,d]) + offs[o]
// GEMM: M=32768, N=512, K=4096, bf16 MFMA 32x32x16 (2382 TF rate vs 2075).
// R17: R16 with the CORRECT swizzle key r&7 (unit h of row r at h ^ (r&7)).
// 8 consecutive lanes -> 8 distinct 16B units -> conflict-free b128 reads
// (R16's (r>>2)&7 key repeated per 4 lanes -> 4-way conflict, 14.7M measured).

#define BATCH 32768
#define NIN   256
#define NOUT  512
#define DDIM  16
#define BM    128
#define BN    512
#define BK    64
#define NKT   ((NIN*DDIM)/BK)     // 64 K-steps
#define TILE_BYTES (BN*BK*2)      // 64 KB per kt pre-swizzled B tile
#define ABYTES (BM*BK*2)          // 16 KB per A buffer
#define BBYTES (BN*BK*2)          // 64 KB per B buffer
#define EPSV  1e-8f
#define INV2PI 0.15915494309189535f

typedef short  bf16x8  __attribute__((ext_vector_type(8)));
typedef float  f32x16  __attribute__((ext_vector_type(16)));

static __device__ __forceinline__ ushort f2bf(float f) {
  union { __hip_bfloat16 h; ushort u; } cv;
  cv.h = __float2bfloat16(f);
  return cv.u;
}

static __device__ __forceinline__ uint cvt_pk(float lo, float hi) {
  uint r;
  asm("v_cvt_pk_bf16_f32 %0, %1, %2" : "=v"(r) : "v"(lo), "v"(hi));
  return r;
}

static __device__ __forceinline__ float sgpr_f(float v) {
  return __builtin_bit_cast(float,
      __builtin_amdgcn_readfirstlane(__builtin_bit_cast(int, v)));
}

// ---------------------------------------------------------------------------
// Prep: cb[o,k] pre-swizzled 512x64 tiles; row o = 128 B (8 16B units);
// unit h stored at h ^ (o&7). Linear gll copy yields the LDS image.
// offs[o] = bias[o] + sum mu_d*scale_d*c[o,i,d].
// ---------------------------------------------------------------------------
__global__ __launch_bounds__(256) void prep_kernel(
    const float* __restrict__ omega, const float* __restrict__ phase,
    const float* __restrict__ c_basis, const float* __restrict__ bias,
    ushort* __restrict__ cb, float* __restrict__ offs)
{
  __shared__ float s_scale[DDIM];
  __shared__ float s_musc[DDIM];
  __shared__ float s_red[4];

  const int o = blockIdx.x;
  const int t = threadIdx.x;

  if (t < DDIM) {
    float w = omega[t];
    float p = phase[t];
    float mu  = expf(-0.5f * w * w) * sinf(p);
    float var = 0.5f * (1.0f - expf(-2.0f * w * w) * cosf(2.0f * p)) - mu * mu;
    float sd  = sqrtf(fmaxf(var, 0.0f));
    float sc  = 1.0f / (sd + EPSV);
    s_scale[t] = sc;
    s_musc[t]  = mu * sc;
  }
  __syncthreads();

  const float* cp = c_basis + ((size_t)o * NIN + t) * DDIM;
  float cv[DDIM];
  {
    const float4* cp4 = (const float4*)cp;
    float4 a = cp4[0], b = cp4[1], c = cp4[2], d = cp4[3];
    cv[0]=a.x; cv[1]=a.y; cv[2]=a.z; cv[3]=a.w;
    cv[4]=b.x; cv[5]=b.y; cv[6]=b.z; cv[7]=b.w;
    cv[8]=c.x; cv[9]=c.y; cv[10]=c.z; cv[11]=c.w;
    cv[12]=d.x; cv[13]=d.y; cv[14]=d.z; cv[15]=d.w;
  }

  float partial = 0.0f;
  uint pk[8];
#pragma unroll
  for (int d = 0; d < DDIM; d += 2) {
    partial += cv[d] * s_musc[d] + cv[d+1] * s_musc[d+1];
    ushort u0 = f2bf(cv[d]   * s_scale[d]);
    ushort u1 = f2bf(cv[d+1] * s_scale[d+1]);
    pk[d >> 1] = (uint)u0 | ((uint)u1 << 16);
  }

  {
    const int r  = o;                 // 0..511
    const int kt = t >> 2;
    const int fo = r & 7;
    char* tile = (char*)cb + (size_t)kt * TILE_BYTES + r * 128;
    const int u0 = (2 * (t & 3))     ^ fo;
    const int u1 = (2 * (t & 3) + 1) ^ fo;
    *(uint4*)(tile + u0 * 16) = make_uint4(pk[0], pk[1], pk[2], pk[3]);
    *(uint4*)(tile + u1 * 16) = make_uint4(pk[4], pk[5], pk[6], pk[7]);
  }

#pragma unroll
  for (int off = 32; off > 0; off >>= 1) partial += __shfl_down(partial, off, 64);
  if ((t & 63) == 0) s_red[t >> 6] = partial;
  __syncthreads();
  if (t == 0) offs[o] = bias[o] + s_red[0] + s_red[1] + s_red[2] + s_red[3];
}

// ---------------------------------------------------------------------------
// GEMM: 128x512 tile, BK=64, 512 threads (8 waves: 2m x 4n, wave = 64x128).
// 32x32x16 fragments: wave tile = 2 m-frags x 4 n-frags, acc = f32x16[2][4].
// LDS: A0[16K] A1[16K] B0[64K] B1[64K] = 160 KB.
// ---------------------------------------------------------------------------
__global__ __launch_bounds__(512, 2) void gemm_kernel(
    const float* __restrict__ x, const float* __restrict__ omega,
    const float* __restrict__ phase, const ushort* __restrict__ cb,
    const float* __restrict__ offs, float* __restrict__ out)
{
  extern __shared__ char lds[];

  const int t    = threadIdx.x;
  const int lane = t & 63;
  const int wid  = t >> 6;
  const int wm   = wid >> 2;       // 0..1
  const int wn   = wid & 3;        // 0..3
  const int row0 = blockIdx.x * BM;

  // uniform omega/phase in SGPRs (readfirstlane) -> zero VGPR cost
  float wv[DDIM], pv[DDIM];
#pragma unroll
  for (int d = 0; d < DDIM; ++d) {
    wv[d] = sgpr_f(omega[d] * INV2PI);
    pv[d] = sgpr_f(phase[d] * INV2PI);
  }

  f32x16 acc[2][4];
#pragma unroll
  for (int m = 0; m < 2; ++m)
#pragma unroll
    for (int n = 0; n < 4; ++n)
#pragma unroll
      for (int j = 0; j < 16; ++j) acc[m][n][j] = 0.f;

  // A staging: thread t -> row t>>2 (0..127), i-slot t&3; 1 x -> 16 sins
  const int arow = t >> 2;
  const int acol = t & 3;
  const float* xbase = x + (size_t)(row0 + arow) * NIN + acol;
  const int afo  = arow & 7;
  const int aw0  = arow * 128 + ((2 * acol)     ^ afo) * 16;
  const int aw1  = arow * 128 + ((2 * acol + 1) ^ afo) * 16;

  const int l31 = lane & 31;
  const int hi2 = lane >> 5;       // 0..1
  const int fr  = l31 & 7;         // swizzle key (per-thread const)

#define GLL(s_, d_) __builtin_amdgcn_global_load_lds(                          \
      (const __attribute__((address_space(1))) void*)(s_),                     \
      (__attribute__((address_space(3))) void*)(d_), 16, 0, 0)

  // 8 global_load_lds: 64 KB B-tile kt_ -> B buffer sb_ (compile-time sb_)
#define ISSUE_B(kt_, sb_)                                                      \
  {                                                                            \
    const char* src = (const char*)cb + (size_t)(kt_) * TILE_BYTES             \
                      + wid * 8192 + lane * 16;                                \
    char* dst = lds + 32768 + (sb_) * BBYTES + wid * 8192;                     \
    GLL(src, dst);                 GLL(src + 1024, dst + 1024);                \
    GLL(src + 2048, dst + 2048);   GLL(src + 3072, dst + 3072);                \
    GLL(src + 4096, dst + 4096);   GLL(src + 5120, dst + 5120);                \
    GLL(src + 6144, dst + 6144);   GLL(src + 7168, dst + 7168);                \
  }

  // 16 sins -> 8 packed bf16-pair words via v_cvt_pk_bf16_f32
#define SINS_ALL(xx_)                                                          \
    _Pragma("unroll")                                                          \
    for (int d = 0; d < DDIM; d += 2) {                                        \
      float s0 = __builtin_amdgcn_sinf(fmaf(wv[d],   (xx_), pv[d]));           \
      float s1 = __builtin_amdgcn_sinf(fmaf(wv[d+1], (xx_), pv[d+1]));         \
      pk[d >> 1] = cvt_pk(s0, s1);                                             \
    }

  // two swizzled ds_write_b128 of the packed sins into A buffer sb_
#define A_WRITE2(sb_)                                                          \
    *(uint4*)(lds + (sb_) * ABYTES + aw0) = make_uint4(pk[0], pk[1], pk[2], pk[3]); \
    *(uint4*)(lds + (sb_) * ABYTES + aw1) = make_uint4(pk[4], pk[5], pk[6], pk[7]);

  // fragment read offset for (rowbase multiple of 32, kk): swizzled unit
#define FRAG_OFF(rb_, kk_) (((rb_) + l31) * 128 + (((2 * (kk_) + hi2) ^ fr) * 16))

  // one kk-pair (half_=0 -> kk 0,1 ; half_=1 -> kk 2,3): 2x(af[2],bfr[4],8 MFMA)
#define MFMA_2K(mb_, half_)                                                    \
  {                                                                            \
    const char* AsB = lds + (mb_) * ABYTES;                                    \
    const char* BsB = lds + 32768 + (mb_) * BBYTES;                            \
    _Pragma("unroll")                                                          \
    for (int kq = 0; kq < 2; ++kq) {                                           \
      const int kk = (half_) * 2 + kq;                                         \
      bf16x8 af[2], bfr[4];                                                    \
      _Pragma("unroll")                                                        \
      for (int m = 0; m < 2; ++m)                                              \
        af[m] = *(const bf16x8*)(AsB + FRAG_OFF(wm * 64 + m * 32, kk));        \
      _Pragma("unroll")                                                        \
      for (int n = 0; n < 4; ++n)                                              \
        bfr[n] = *(const bf16x8*)(BsB + FRAG_OFF(wn * 128 + n * 32, kk));      \
      __builtin_amdgcn_s_setprio(1);                                           \
      _Pragma("unroll")                                                        \
      for (int m = 0; m < 2; ++m)                                              \
        _Pragma("unroll")                                                      \
        for (int n = 0; n < 4; ++n)                                            \
          acc[m][n] = __builtin_amdgcn_mfma_f32_32x32x16_bf16(                 \
              af[m], bfr[n], acc[m][n], 0, 0, 0);                              \
      __builtin_amdgcn_s_setprio(0);                                           \
    }                                                                          \
  }

#define SB __builtin_amdgcn_sched_barrier(0);

#define CBAR(vm_)                                                              \
  __builtin_amdgcn_sched_barrier(0);                                           \
  asm volatile("s_waitcnt vmcnt(" #vm_ ") lgkmcnt(0)" ::: "memory");           \
  __builtin_amdgcn_s_barrier();                                                \
  __builtin_amdgcn_sched_barrier(0);

  // R13 sandwich body with 32x32 fragments
#define BODY(kt_, mb_, sb_, XU_, XL_)                                          \
  {                                                                            \
    ISSUE_B(((kt_) + 1 < NKT ? (kt_) + 1 : NKT - 1), sb_);                     \
    XL_ = xbase[((kt_) + 2 < NKT ? (kt_) + 2 : NKT - 1) * 4];                  \
    SB                                                                         \
    MFMA_2K(mb_, 0)                                                            \
    SB                                                                         \
    uint pk[8];                                                                \
    SINS_ALL(XU_)                                                              \
    A_WRITE2(sb_)                                                              \
    SB                                                                         \
    MFMA_2K(mb_, 1)                                                            \
    CBAR(1)                                                                    \
  }

  // ---- prologue ----
  float xs0, xs1;
  {
    float xp = xbase[0];
    SB
    ISSUE_B(0, 0);
    SB
    xs1 = xbase[4];
    SB
    {
      uint pk[8];
      SINS_ALL(xp)
      A_WRITE2(0)
    }
    CBAR(1)                       // drains B(0)+x(0), keeps xs1 in flight
  }

  for (int kt = 0; kt < NKT; kt += 2) {
    BODY(kt,     0, 1, xs1, xs0)
    BODY(kt + 1, 1, 0, xs0, xs1)
  }

  // ---- epilogue: y = acc + offs[o] ; C/D map: col=l31, row=(reg&3)+8(reg>>2)+4*hi2
#pragma unroll
  for (int n = 0; n < 4; ++n) {
    int col = wn * 128 + n * 32 + l31;
    float off = offs[col];
#pragma unroll
    for (int m = 0; m < 2; ++m) {
      int rbase = row0 + wm * 64 + m * 32 + hi2 * 4;
#pragma unroll
      for (int reg = 0; reg < 16; ++reg) {
        int row = rbase + (reg & 3) + 8 * (reg >> 2);
        out[(size_t)row * NOUT + col] = acc[m][n][reg] + off;
      }
    }
  }
}

// ---------------------------------------------------------------------------
extern "C" void kernel_launch(void* const* d_in, const int* in_sizes, int n_in,
                              void* d_out, int out_size, void* d_ws, size_t ws_size,
                              hipStream_t stream) {
  const float* x       = (const float*)d_in[0];
  const float* omega   = (const float*)d_in[1];
  const float* phase   = (const float*)d_in[2];
  const float* c_basis = (const float*)d_in[3];
  const float* bias    = (const float*)d_in[4];
  float* out = (float*)d_out;

  float*  offs = (float*)d_ws;
  ushort* cb   = (ushort*)((char*)d_ws + 2048);

  hipFuncSetAttribute((const void*)gemm_kernel,
                      hipFuncAttributeMaxDynamicSharedMemorySize, 163840);

  prep_kernel<<<NOUT, 256, 0, stream>>>(omega, phase, c_basis, bias, cb, offs);
  gemm_kernel<<<BATCH / BM, 512, 163840, stream>>>(x, omega, phase, cb, offs, out);
}

// Round 18
// 140.333 us; speedup vs baseline: 1.0449x; 1.0346x over previous
//
#include <hip/hip_runtime.h>
#include <hip/hip_bf16.h>

// SineLayer: y[b,o] = sum_{i,d} sin(w_d*x[b,i]+p_d) * (scale_d*c[o,i,d]) + offs[o]
// GEMM: M=32768, N=512, K=4096, bf16 MFMA 32x32x16.
// R18: swizzle key f(r) = (r&7) ^ ((r>>3)&3). Lane pairs (l,l+8)/(l,l+16)/
// (l,l+32) then hit XOR-distinct 16B units (R17's key collided l with l+16:
// 12.58M conflicts). Everything else = R17 (R13 sandwich, 32x32 frags).

#define BATCH 32768
#define NIN   256
#define NOUT  512
#define DDIM  16
#define BM    128
#define BN    512
#define BK    64
#define NKT   ((NIN*DDIM)/BK)     // 64 K-steps
#define TILE_BYTES (BN*BK*2)      // 64 KB per kt pre-swizzled B tile
#define ABYTES (BM*BK*2)          // 16 KB per A buffer
#define BBYTES (BN*BK*2)          // 64 KB per B buffer
#define EPSV  1e-8f
#define INV2PI 0.15915494309189535f

#define FKEY(r_) (((r_) & 7) ^ (((r_) >> 3) & 3))

typedef short  bf16x8  __attribute__((ext_vector_type(8)));
typedef float  f32x16  __attribute__((ext_vector_type(16)));

static __device__ __forceinline__ ushort f2bf(float f) {
  union { __hip_bfloat16 h; ushort u; } cv;
  cv.h = __float2bfloat16(f);
  return cv.u;
}

static __device__ __forceinline__ uint cvt_pk(float lo, float hi) {
  uint r;
  asm("v_cvt_pk_bf16_f32 %0, %1, %2" : "=v"(r) : "v"(lo), "v"(hi));
  return r;
}

static __device__ __forceinline__ float sgpr_f(float v) {
  return __builtin_bit_cast(float,
      __builtin_amdgcn_readfirstlane(__builtin_bit_cast(int, v)));
}

// ---------------------------------------------------------------------------
// Prep: cb[o,k] pre-swizzled 512x64 tiles; row o = 128 B (8 16B units);
// unit h stored at h ^ FKEY(o). Linear gll copy yields the LDS image.
// offs[o] = bias[o] + sum mu_d*scale_d*c[o,i,d].
// ---------------------------------------------------------------------------
__global__ __launch_bounds__(256) void prep_kernel(
    const float* __restrict__ omega, const float* __restrict__ phase,
    const float* __restrict__ c_basis, const float* __restrict__ bias,
    ushort* __restrict__ cb, float* __restrict__ offs)
{
  __shared__ float s_scale[DDIM];
  __shared__ float s_musc[DDIM];
  __shared__ float s_red[4];

  const int o = blockIdx.x;
  const int t = threadIdx.x;

  if (t < DDIM) {
    float w = omega[t];
    float p = phase[t];
    float mu  = expf(-0.5f * w * w) * sinf(p);
    float var = 0.5f * (1.0f - expf(-2.0f * w * w) * cosf(2.0f * p)) - mu * mu;
    float sd  = sqrtf(fmaxf(var, 0.0f));
    float sc  = 1.0f / (sd + EPSV);
    s_scale[t] = sc;
    s_musc[t]  = mu * sc;
  }
  __syncthreads();

  const float* cp = c_basis + ((size_t)o * NIN + t) * DDIM;
  float cv[DDIM];
  {
    const float4* cp4 = (const float4*)cp;
    float4 a = cp4[0], b = cp4[1], c = cp4[2], d = cp4[3];
    cv[0]=a.x; cv[1]=a.y; cv[2]=a.z; cv[3]=a.w;
    cv[4]=b.x; cv[5]=b.y; cv[6]=b.z; cv[7]=b.w;
    cv[8]=c.x; cv[9]=c.y; cv[10]=c.z; cv[11]=c.w;
    cv[12]=d.x; cv[13]=d.y; cv[14]=d.z; cv[15]=d.w;
  }

  float partial = 0.0f;
  uint pk[8];
#pragma unroll
  for (int d = 0; d < DDIM; d += 2) {
    partial += cv[d] * s_musc[d] + cv[d+1] * s_musc[d+1];
    ushort u0 = f2bf(cv[d]   * s_scale[d]);
    ushort u1 = f2bf(cv[d+1] * s_scale[d+1]);
    pk[d >> 1] = (uint)u0 | ((uint)u1 << 16);
  }

  {
    const int r  = o;                 // 0..511
    const int kt = t >> 2;
    const int fo = FKEY(r);
    char* tile = (char*)cb + (size_t)kt * TILE_BYTES + r * 128;
    const int u0 = (2 * (t & 3))     ^ fo;
    const int u1 = (2 * (t & 3) + 1) ^ fo;
    *(uint4*)(tile + u0 * 16) = make_uint4(pk[0], pk[1], pk[2], pk[3]);
    *(uint4*)(tile + u1 * 16) = make_uint4(pk[4], pk[5], pk[6], pk[7]);
  }

#pragma unroll
  for (int off = 32; off > 0; off >>= 1) partial += __shfl_down(partial, off, 64);
  if ((t & 63) == 0) s_red[t >> 6] = partial;
  __syncthreads();
  if (t == 0) offs[o] = bias[o] + s_red[0] + s_red[1] + s_red[2] + s_red[3];
}

// ---------------------------------------------------------------------------
// GEMM: 128x512 tile, BK=64, 512 threads (8 waves: 2m x 4n, wave = 64x128).
// 32x32x16 fragments: wave tile = 2 m-frags x 4 n-frags, acc = f32x16[2][4].
// LDS: A0[16K] A1[16K] B0[64K] B1[64K] = 160 KB.
// ---------------------------------------------------------------------------
__global__ __launch_bounds__(512, 2) void gemm_kernel(
    const float* __restrict__ x, const float* __restrict__ omega,
    const float* __restrict__ phase, const ushort* __restrict__ cb,
    const float* __restrict__ offs, float* __restrict__ out)
{
  extern __shared__ char lds[];

  const int t    = threadIdx.x;
  const int lane = t & 63;
  const int wid  = t >> 6;
  const int wm   = wid >> 2;       // 0..1
  const int wn   = wid & 3;        // 0..3
  const int row0 = blockIdx.x * BM;

  // uniform omega/phase in SGPRs (readfirstlane) -> zero VGPR cost
  float wv[DDIM], pv[DDIM];
#pragma unroll
  for (int d = 0; d < DDIM; ++d) {
    wv[d] = sgpr_f(omega[d] * INV2PI);
    pv[d] = sgpr_f(phase[d] * INV2PI);
  }

  f32x16 acc[2][4];
#pragma unroll
  for (int m = 0; m < 2; ++m)
#pragma unroll
    for (int n = 0; n < 4; ++n)
#pragma unroll
      for (int j = 0; j < 16; ++j) acc[m][n][j] = 0.f;

  // A staging: thread t -> row t>>2 (0..127), i-slot t&3; 1 x -> 16 sins
  const int arow = t >> 2;
  const int acol = t & 3;
  const float* xbase = x + (size_t)(row0 + arow) * NIN + acol;
  const int afo  = FKEY(arow);
  const int aw0  = arow * 128 + ((2 * acol)     ^ afo) * 16;
  const int aw1  = arow * 128 + ((2 * acol + 1) ^ afo) * 16;

  const int l31 = lane & 31;
  const int hi2 = lane >> 5;       // 0..1
  const int fr  = FKEY(l31);       // swizzle key (per-thread const)

#define GLL(s_, d_) __builtin_amdgcn_global_load_lds(                          \
      (const __attribute__((address_space(1))) void*)(s_),                     \
      (__attribute__((address_space(3))) void*)(d_), 16, 0, 0)

  // 8 global_load_lds: 64 KB B-tile kt_ -> B buffer sb_ (compile-time sb_)
#define ISSUE_B(kt_, sb_)                                                      \
  {                                                                            \
    const char* src = (const char*)cb + (size_t)(kt_) * TILE_BYTES             \
                      + wid * 8192 + lane * 16;                                \
    char* dst = lds + 32768 + (sb_) * BBYTES + wid * 8192;                     \
    GLL(src, dst);                 GLL(src + 1024, dst + 1024);                \
    GLL(src + 2048, dst + 2048);   GLL(src + 3072, dst + 3072);                \
    GLL(src + 4096, dst + 4096);   GLL(src + 5120, dst + 5120);                \
    GLL(src + 6144, dst + 6144);   GLL(src + 7168, dst + 7168);                \
  }

  // 16 sins -> 8 packed bf16-pair words via v_cvt_pk_bf16_f32
#define SINS_ALL(xx_)                                                          \
    _Pragma("unroll")                                                          \
    for (int d = 0; d < DDIM; d += 2) {                                        \
      float s0 = __builtin_amdgcn_sinf(fmaf(wv[d],   (xx_), pv[d]));           \
      float s1 = __builtin_amdgcn_sinf(fmaf(wv[d+1], (xx_), pv[d+1]));         \
      pk[d >> 1] = cvt_pk(s0, s1);                                             \
    }

  // two swizzled ds_write_b128 of the packed sins into A buffer sb_
#define A_WRITE2(sb_)                                                          \
    *(uint4*)(lds + (sb_) * ABYTES + aw0) = make_uint4(pk[0], pk[1], pk[2], pk[3]); \
    *(uint4*)(lds + (sb_) * ABYTES + aw1) = make_uint4(pk[4], pk[5], pk[6], pk[7]);

  // fragment read offset for (rowbase multiple of 32, kk): swizzled unit
#define FRAG_OFF(rb_, kk_) (((rb_) + l31) * 128 + (((2 * (kk_) + hi2) ^ fr) * 16))

  // one kk-pair (half_=0 -> kk 0,1 ; half_=1 -> kk 2,3): 2x(af[2],bfr[4],8 MFMA)
#define MFMA_2K(mb_, half_)                                                    \
  {                                                                            \
    const char* AsB = lds + (mb_) * ABYTES;                                    \
    const char* BsB = lds + 32768 + (mb_) * BBYTES;                            \
    _Pragma("unroll")                                                          \
    for (int kq = 0; kq < 2; ++kq) {                                           \
      const int kk = (half_) * 2 + kq;                                         \
      bf16x8 af[2], bfr[4];                                                    \
      _Pragma("unroll")                                                        \
      for (int m = 0; m < 2; ++m)                                              \
        af[m] = *(const bf16x8*)(AsB + FRAG_OFF(wm * 64 + m * 32, kk));        \
      _Pragma("unroll")                                                        \
      for (int n = 0; n < 4; ++n)                                              \
        bfr[n] = *(const bf16x8*)(BsB + FRAG_OFF(wn * 128 + n * 32, kk));      \
      __builtin_amdgcn_s_setprio(1);                                           \
      _Pragma("unroll")                                                        \
      for (int m = 0; m < 2; ++m)                                              \
        _Pragma("unroll")                                                      \
        for (int n = 0; n < 4; ++n)                                            \
          acc[m][n] = __builtin_amdgcn_mfma_f32_32x32x16_bf16(                 \
              af[m], bfr[n], acc[m][n], 0, 0, 0);                              \
      __builtin_amdgcn_s_setprio(0);                                           \
    }                                                                          \
  }

#define SB __builtin_amdgcn_sched_barrier(0);

#define CBAR(vm_)                                                              \
  __builtin_amdgcn_sched_barrier(0);                                           \
  asm volatile("s_waitcnt vmcnt(" #vm_ ") lgkmcnt(0)" ::: "memory");           \
  __builtin_amdgcn_s_barrier();                                                \
  __builtin_amdgcn_sched_barrier(0);

  // R13 sandwich body with 32x32 fragments
#define BODY(kt_, mb_, sb_, XU_, XL_)                                          \
  {                                                                            \
    ISSUE_B(((kt_) + 1 < NKT ? (kt_) + 1 : NKT - 1), sb_);                     \
    XL_ = xbase[((kt_) + 2 < NKT ? (kt_) + 2 : NKT - 1) * 4];                  \
    SB                                                                         \
    MFMA_2K(mb_, 0)                                                            \
    SB                                                                         \
    uint pk[8];                                                                \
    SINS_ALL(XU_)                                                              \
    A_WRITE2(sb_)                                                              \
    SB                                                                         \
    MFMA_2K(mb_, 1)                                                            \
    CBAR(1)                                                                    \
  }

  // ---- prologue ----
  float xs0, xs1;
  {
    float xp = xbase[0];
    SB
    ISSUE_B(0, 0);
    SB
    xs1 = xbase[4];
    SB
    {
      uint pk[8];
      SINS_ALL(xp)
      A_WRITE2(0)
    }
    CBAR(1)                       // drains B(0)+x(0), keeps xs1 in flight
  }

  for (int kt = 0; kt < NKT; kt += 2) {
    BODY(kt,     0, 1, xs1, xs0)
    BODY(kt + 1, 1, 0, xs0, xs1)
  }

  // ---- epilogue: y = acc + offs[o] ; C/D map: col=l31, row=(reg&3)+8(reg>>2)+4*hi2
#pragma unroll
  for (int n = 0; n < 4; ++n) {
    int col = wn * 128 + n * 32 + l31;
    float off = offs[col];
#pragma unroll
    for (int m = 0; m < 2; ++m) {
      int rbase = row0 + wm * 64 + m * 32 + hi2 * 4;
#pragma unroll
      for (int reg = 0; reg < 16; ++reg) {
        int row = rbase + (reg & 3) + 8 * (reg >> 2);
        out[(size_t)row * NOUT + col] = acc[m][n][reg] + off;
      }
    }
  }
}

// ---------------------------------------------------------------------------
extern "C" void kernel_launch(void* const* d_in, const int* in_sizes, int n_in,
                              void* d_out, int out_size, void* d_ws, size_t ws_size,
                              hipStream_t stream) {
  const float* x       = (const float*)d_in[0];
  const float* omega   = (const float*)d_in[1];
  const float* phase   = (const float*)d_in[2];
  const float* c_basis = (const float*)d_in[3];
  const float* bias    = (const float*)d_in[4];
  float* out = (float*)d_out;

  float*  offs = (float*)d_ws;
  ushort* cb   = (ushort*)((char*)d_ws + 2048);

  hipFuncSetAttribute((const void*)gemm_kernel,
                      hipFuncAttributeMaxDynamicSharedMemorySize, 163840);

  prep_kernel<<<NOUT, 256, 0, stream>>>(omega, phase, c_basis, bias, cb, offs);
  gemm_kernel<<<BATCH / BM, 512, 163840, stream>>>(x, omega, phase, cb, offs, out);
}

// Round 19
// 127.950 us; speedup vs baseline: 1.1460x; 1.0968x over previous
//
#include <hip/hip_runtime.h>
#include <hip/hip_bf16.h>

// SineLayer: y[b,o] = sum_{i,d} sin(w_d*x[b,i]+p_d) * (scale_d*c[o,i,d]) + offs[o]
// GEMM: M=32768, N=512, K=4096, bf16 MFMA 16x16x32.
// R19: R13 (best, 127.6us) + GLL issue split 4+4 around MFMA_HALF(0) to
// smooth the LDS-writeback burst against fragment reads. x-load stays last
// in VMEM issue order so CBAR's vmcnt(1) drains exactly the 8 B-glls.

#define BATCH 32768
#define NIN   256
#define NOUT  512
#define DDIM  16
#define BM    128
#define BN    512
#define BK    64
#define NKT   ((NIN*DDIM)/BK)     // 64 K-steps
#define TILE_BYTES (BN*BK*2)      // 64 KB per kt pre-swizzled B tile
#define ABYTES (BM*BK*2)          // 16 KB per A buffer
#define BBYTES (BN*BK*2)          // 64 KB per B buffer
#define EPSV  1e-8f
#define INV2PI 0.15915494309189535f

typedef short  bf16x8 __attribute__((ext_vector_type(8)));
typedef float  f32x4  __attribute__((ext_vector_type(4)));

static __device__ __forceinline__ ushort f2bf(float f) {
  union { __hip_bfloat16 h; ushort u; } cv;
  cv.h = __float2bfloat16(f);
  return cv.u;
}

static __device__ __forceinline__ uint cvt_pk(float lo, float hi) {
  uint r;
  asm("v_cvt_pk_bf16_f32 %0, %1, %2" : "=v"(r) : "v"(lo), "v"(hi));
  return r;
}

static __device__ __forceinline__ float sgpr_f(float v) {
  return __builtin_bit_cast(float,
      __builtin_amdgcn_readfirstlane(__builtin_bit_cast(int, v)));
}

// ---------------------------------------------------------------------------
// Prep: cb[o,k] = bf16(scale_d * c[o,i,d]) as ONE pre-swizzled 512x64 tile per
// kt (byte = (r*128 + kloc*2) ^ ((r&7)<<4), r = o) so a LINEAR global_load_lds
// copy yields the swizzled LDS image. offs[o] = bias[o] + sum mu*scale*c.
// ---------------------------------------------------------------------------
__global__ __launch_bounds__(256) void prep_kernel(
    const float* __restrict__ omega, const float* __restrict__ phase,
    const float* __restrict__ c_basis, const float* __restrict__ bias,
    ushort* __restrict__ cb, float* __restrict__ offs)
{
  __shared__ float s_scale[DDIM];
  __shared__ float s_musc[DDIM];
  __shared__ float s_red[4];

  const int o = blockIdx.x;
  const int t = threadIdx.x;

  if (t < DDIM) {
    float w = omega[t];
    float p = phase[t];
    float mu  = expf(-0.5f * w * w) * sinf(p);
    float var = 0.5f * (1.0f - expf(-2.0f * w * w) * cosf(2.0f * p)) - mu * mu;
    float sd  = sqrtf(fmaxf(var, 0.0f));
    float sc  = 1.0f / (sd + EPSV);
    s_scale[t] = sc;
    s_musc[t]  = mu * sc;
  }
  __syncthreads();

  const float* cp = c_basis + ((size_t)o * NIN + t) * DDIM;
  float cv[DDIM];
  {
    const float4* cp4 = (const float4*)cp;
    float4 a = cp4[0], b = cp4[1], c = cp4[2], d = cp4[3];
    cv[0]=a.x; cv[1]=a.y; cv[2]=a.z; cv[3]=a.w;
    cv[4]=b.x; cv[5]=b.y; cv[6]=b.z; cv[7]=b.w;
    cv[8]=c.x; cv[9]=c.y; cv[10]=c.z; cv[11]=c.w;
    cv[12]=d.x; cv[13]=d.y; cv[14]=d.z; cv[15]=d.w;
  }

  float partial = 0.0f;
  uint pk[8];
#pragma unroll
  for (int d = 0; d < DDIM; d += 2) {
    partial += cv[d] * s_musc[d] + cv[d+1] * s_musc[d+1];
    ushort u0 = f2bf(cv[d]   * s_scale[d]);
    ushort u1 = f2bf(cv[d+1] * s_scale[d+1]);
    pk[d >> 1] = (uint)u0 | ((uint)u1 << 16);
  }

  {
    const int r   = o;               // 0..511
    const int kt  = t >> 2;
    const int swz = (r & 7) << 4;
    char* tile = (char*)cb + (size_t)kt * TILE_BYTES;
    int b0 = r * 128 + (t & 3) * 32;
    *(uint4*)(tile + ((b0     ) ^ swz)) = make_uint4(pk[0], pk[1], pk[2], pk[3]);
    *(uint4*)(tile + ((b0 + 16) ^ swz)) = make_uint4(pk[4], pk[5], pk[6], pk[7]);
  }

#pragma unroll
  for (int off = 32; off > 0; off >>= 1) partial += __shfl_down(partial, off, 64);
  if ((t & 63) == 0) s_red[t >> 6] = partial;
  __syncthreads();
  if (t == 0) offs[o] = bias[o] + s_red[0] + s_red[1] + s_red[2] + s_red[3];
}

// ---------------------------------------------------------------------------
// GEMM: 128x512 tile, BK=64, 512 threads (8 waves: 2m x 4n, wave = 64x128).
// LDS: A0[16K] A1[16K] B0[64K] B1[64K] = 160 KB.
// ---------------------------------------------------------------------------
__global__ __launch_bounds__(512, 2) void gemm_kernel(
    const float* __restrict__ x, const float* __restrict__ omega,
    const float* __restrict__ phase, const ushort* __restrict__ cb,
    const float* __restrict__ offs, float* __restrict__ out)
{
  extern __shared__ char lds[];

  const int t    = threadIdx.x;
  const int lane = t & 63;
  const int wid  = t >> 6;
  const int wm   = wid >> 2;       // 0..1
  const int wn   = wid & 3;        // 0..3
  const int row0 = blockIdx.x * BM;

  // uniform omega/phase in SGPRs (readfirstlane) -> zero VGPR cost
  float wv[DDIM], pv[DDIM];
#pragma unroll
  for (int d = 0; d < DDIM; ++d) {
    wv[d] = sgpr_f(omega[d] * INV2PI);
    pv[d] = sgpr_f(phase[d] * INV2PI);
  }

  f32x4 acc[4][8];
#pragma unroll
  for (int m = 0; m < 4; ++m)
#pragma unroll
    for (int n = 0; n < 8; ++n) acc[m][n] = (f32x4){0.f, 0.f, 0.f, 0.f};

  // A staging: thread t -> row t>>2 (0..127), i-slot t&3; 1 x -> 16 sins
  const int arow = t >> 2;
  const int acol = t & 3;
  const float* xbase = x + (size_t)(row0 + arow) * NIN + acol;
  const int aswz = (arow & 7) << 4;
  const int ab0  = arow * 128 + acol * 32;

  const int hi  = lane >> 4;       // 0..3
  const int l15 = lane & 15;

#define GLL(s_, d_) __builtin_amdgcn_global_load_lds(                          \
      (const __attribute__((address_space(1))) void*)(s_),                     \
      (__attribute__((address_space(3))) void*)(d_), 16, 0, 0)

  // first/second half of the 8 global_load_lds for B-tile kt_ -> buffer sb_
#define ISSUE_B_LO(kt_, sb_)                                                   \
  {                                                                            \
    const char* src = (const char*)cb + (size_t)(kt_) * TILE_BYTES             \
                      + wid * 8192 + lane * 16;                                \
    char* dst = lds + 32768 + (sb_) * BBYTES + wid * 8192;                     \
    GLL(src, dst);                 GLL(src + 1024, dst + 1024);                \
    GLL(src + 2048, dst + 2048);   GLL(src + 3072, dst + 3072);                \
  }
#define ISSUE_B_HI(kt_, sb_)                                                   \
  {                                                                            \
    const char* src = (const char*)cb + (size_t)(kt_) * TILE_BYTES             \
                      + wid * 8192 + lane * 16;                                \
    char* dst = lds + 32768 + (sb_) * BBYTES + wid * 8192;                     \
    GLL(src + 4096, dst + 4096);   GLL(src + 5120, dst + 5120);                \
    GLL(src + 6144, dst + 6144);   GLL(src + 7168, dst + 7168);                \
  }

  // 16 sins -> 8 packed bf16-pair words via v_cvt_pk_bf16_f32
#define SINS_ALL(xx_)                                                          \
    _Pragma("unroll")                                                          \
    for (int d = 0; d < DDIM; d += 2) {                                        \
      float s0 = __builtin_amdgcn_sinf(fmaf(wv[d],   (xx_), pv[d]));           \
      float s1 = __builtin_amdgcn_sinf(fmaf(wv[d+1], (xx_), pv[d+1]));         \
      pk[d >> 1] = cvt_pk(s0, s1);                                             \
    }

  // two swizzled ds_write_b128 of the packed sins into A buffer sb_
#define A_WRITE2(sb_)                                                          \
    *(uint4*)(lds + (sb_) * ABYTES + ((ab0     ) ^ aswz)) =                    \
        make_uint4(pk[0], pk[1], pk[2], pk[3]);                                \
    *(uint4*)(lds + (sb_) * ABYTES + ((ab0 + 16) ^ aswz)) =                    \
        make_uint4(pk[4], pk[5], pk[6], pk[7]);

  // one kk-half (32 MFMAs), B-frags in 4-reg chunks (spill-safe)
#define MFMA_HALF(mb_, kk_)                                                    \
  {                                                                            \
    const char* AsB = lds + (mb_) * ABYTES;                                    \
    const char* BsB = lds + 32768 + (mb_) * BBYTES;                            \
    bf16x8 af[4];                                                              \
    _Pragma("unroll")                                                          \
    for (int m = 0; m < 4; ++m) {                                              \
      int rr = wm * 64 + m * 16 + l15;                                         \
      af[m] = *(const bf16x8*)(AsB + ((rr*128 + (kk_)*64 + hi*16) ^ ((rr&7)<<4))); \
    }                                                                          \
    __builtin_amdgcn_s_setprio(1);                                             \
    _Pragma("unroll")                                                          \
    for (int nh = 0; nh < 2; ++nh) {                                           \
      bf16x8 bfr[4];                                                           \
      _Pragma("unroll")                                                        \
      for (int n4 = 0; n4 < 4; ++n4) {                                         \
        int rr = wn * 128 + (nh * 4 + n4) * 16 + l15;                          \
        bfr[n4] = *(const bf16x8*)(BsB + ((rr*128 + (kk_)*64 + hi*16) ^ ((rr&7)<<4))); \
      }                                                                        \
      _Pragma("unroll")                                                        \
      for (int m = 0; m < 4; ++m)                                              \
        _Pragma("unroll")                                                      \
        for (int n4 = 0; n4 < 4; ++n4)                                         \
          acc[m][nh * 4 + n4] = __builtin_amdgcn_mfma_f32_16x16x32_bf16(       \
              af[m], bfr[n4], acc[m][nh * 4 + n4], 0, 0, 0);                   \
    }                                                                          \
    __builtin_amdgcn_s_setprio(0);                                             \
  }

#define SB __builtin_amdgcn_sched_barrier(0);

#define CBAR(vm_)                                                              \
  __builtin_amdgcn_sched_barrier(0);                                           \
  asm volatile("s_waitcnt vmcnt(" #vm_ ") lgkmcnt(0)" ::: "memory");           \
  __builtin_amdgcn_s_barrier();                                                \
  __builtin_amdgcn_sched_barrier(0);

  // Sandwich body with split GLL issue (4 before, 4 after MFMA_HALF(0));
  // x-load issued LAST of the 9 VMEM ops -> vmcnt(1) drains exactly the glls.
#define BODY(kt_, mb_, sb_, XU_, XL_)                                          \
  {                                                                            \
    const int ktn = ((kt_) + 1 < NKT ? (kt_) + 1 : NKT - 1);                   \
    ISSUE_B_LO(ktn, sb_);                                                      \
    SB                                                                         \
    MFMA_HALF(mb_, 0)                                                          \
    SB                                                                         \
    ISSUE_B_HI(ktn, sb_);                                                      \
    XL_ = xbase[((kt_) + 2 < NKT ? (kt_) + 2 : NKT - 1) * 4];                  \
    SB                                                                         \
    uint pk[8];                                                                \
    SINS_ALL(XU_)                                                              \
    A_WRITE2(sb_)                                                              \
    SB                                                                         \
    MFMA_HALF(mb_, 1)                                                          \
    CBAR(1)                                                                    \
  }

  // ---- prologue ----
  float xs0, xs1;
  {
    float xp = xbase[0];
    SB
    ISSUE_B_LO(0, 0);
    ISSUE_B_HI(0, 0);
    SB
    xs1 = xbase[4];
    SB
    {
      uint pk[8];
      SINS_ALL(xp)
      A_WRITE2(0)
    }
    CBAR(1)                       // drains B(0)+x(0), keeps xs1 in flight
  }

  for (int kt = 0; kt < NKT; kt += 2) {
    BODY(kt,     0, 1, xs1, xs0)
    BODY(kt + 1, 1, 0, xs0, xs1)
  }

  // ---- epilogue: y = acc + offs[o] ----
#pragma unroll
  for (int n = 0; n < 8; ++n) {
    int col = wn * 128 + n * 16 + l15;
    float off = offs[col];
#pragma unroll
    for (int m = 0; m < 4; ++m) {
      int row = row0 + wm * 64 + m * 16 + hi * 4;
      float* op = out + (size_t)row * NOUT + col;
#pragma unroll
      for (int j = 0; j < 4; ++j)
        op[(size_t)j * NOUT] = acc[m][n][j] + off;
    }
  }
}

// ---------------------------------------------------------------------------
extern "C" void kernel_launch(void* const* d_in, const int* in_sizes, int n_in,
                              void* d_out, int out_size, void* d_ws, size_t ws_size,
                              hipStream_t stream) {
  const float* x       = (const float*)d_in[0];
  const float* omega   = (const float*)d_in[1];
  const float* phase   = (const float*)d_in[2];
  const float* c_basis = (const float*)d_in[3];
  const float* bias    = (const float*)d_in[4];
  float* out = (float*)d_out;

  float*  offs = (float*)d_ws;
  ushort* cb   = (ushort*)((char*)d_ws + 2048);

  hipFuncSetAttribute((const void*)gemm_kernel,
                      hipFuncAttributeMaxDynamicSharedMemorySize, 163840);

  prep_kernel<<<NOUT, 256, 0, stream>>>(omega, phase, c_basis, bias, cb, offs);
  gemm_kernel<<<BATCH / BM, 512, 163840, stream>>>(x, omega, phase, cb, offs, out);
}